// Round 1
// baseline (398.364 us; speedup 1.0000x reference)
//
#include <hip/hip_runtime.h>
#include <math.h>

typedef _Float16 h8f16 __attribute__((ext_vector_type(8)));
typedef float f32x4 __attribute__((ext_vector_type(4)));

#define MFMA16(a, b, c) __builtin_amdgcn_mfma_f32_16x16x32_f16((a), (b), (c), 0, 0, 0)

// ---------------------------------------------------------------------------
// z0 = (past[:,0,:] @ xproj_w.T + xproj_b) @ z0_w.T + z0_b      (fp32 exact)
// grid: B blocks x 128 threads
// ---------------------------------------------------------------------------
__global__ __launch_bounds__(128) void z0_kernel(
    const float* __restrict__ past,
    const float* __restrict__ xw, const float* __restrict__ xb,
    const float* __restrict__ zw, const float* __restrict__ zb,
    float* __restrict__ zbuf)
{
    __shared__ float p[32];
    __shared__ float x0[128];
    const int b = blockIdx.x;
    const int tid = threadIdx.x;
    if (tid < 32) p[tid] = past[(long)b * 512 * 32 + tid];
    __syncthreads();
    float s = xb[tid];
#pragma unroll
    for (int c = 0; c < 32; ++c) s += p[c] * xw[tid * 32 + c];
    x0[tid] = s;
    __syncthreads();
    float z = zb[tid];
    for (int k = 0; k < 128; ++k) z += x0[k] * zw[tid * 128 + k];
    zbuf[(long)b * 128 + tid] = z;
}

// ---------------------------------------------------------------------------
// The ODE mega-kernel: 32 RK4 steps x 4 odef evals, all in one launch.
// grid: 128 blocks (16 batch rows each) x 256 threads (4 waves).
// Wave q owns output-feature columns [32q, 32q+32) of every layer.
// All weights live in registers as f16 MFMA B-fragments for the whole kernel.
// ---------------------------------------------------------------------------
__global__ __launch_bounds__(256, 1) void ode_kernel(
    const float* __restrict__ past,
    const float* __restrict__ xproj_w, const float* __restrict__ xproj_b,
    const float* __restrict__ ln_g, const float* __restrict__ ln_b,
    const float* __restrict__ w1, const float* __restrict__ b1,
    const float* __restrict__ w2, const float* __restrict__ b2,
    const float* __restrict__ w3, const float* __restrict__ b3,
    float* __restrict__ zbuf)
{
    __shared__ _Float16 hbuf[16][264];   // [zn(128) | xt(128)], +8 pad
    __shared__ _Float16 h1buf[16][136];
    __shared__ _Float16 h2buf[16][136];
    __shared__ _Float16 bxbuf[16][40];   // blended past (K=32)
    __shared__ float zS[16][132];        // ODE state
    __shared__ float kS[16][132];        // last k (for z + c*k input)

    const int tid  = threadIdx.x;
    const int lane = tid & 63;
    const int wq   = tid >> 6;     // wave = N-quarter
    const int lrow = lane & 15;
    const int lhi  = lane >> 4;
    const int b0   = blockIdx.x * 16;

    // ---- preload weights into register B-fragments ----
    // B-frag (tile n0, kstep ks): lane holds w[n0+lrow][ks*32 + lhi*8 + j]
    h8f16 w1f[2][8], w2f[2][4], w3f[2][4], xpf[2];
    float b1r[2], b2r[2], b3r[2], xbr[2];
#pragma unroll
    for (int nt = 0; nt < 2; ++nt) {
        const int n = wq * 32 + nt * 16 + lrow;
#pragma unroll
        for (int ks = 0; ks < 8; ++ks) {
            const float* s = w1 + n * 256 + ks * 32 + lhi * 8;
            h8f16 v;
#pragma unroll
            for (int j = 0; j < 8; ++j) v[j] = (_Float16)s[j];
            w1f[nt][ks] = v;
        }
#pragma unroll
        for (int ks = 0; ks < 4; ++ks) {
            const float* s2 = w2 + n * 128 + ks * 32 + lhi * 8;
            const float* s3 = w3 + n * 128 + ks * 32 + lhi * 8;
            h8f16 v2, v3;
#pragma unroll
            for (int j = 0; j < 8; ++j) { v2[j] = (_Float16)s2[j]; v3[j] = (_Float16)s3[j]; }
            w2f[nt][ks] = v2; w3f[nt][ks] = v3;
        }
        {
            const float* s = xproj_w + n * 32 + lhi * 8;
            h8f16 v;
#pragma unroll
            for (int j = 0; j < 8; ++j) v[j] = (_Float16)s[j];
            xpf[nt] = v;
        }
        b1r[nt] = b1[n]; b2r[nt] = b2[n]; b3r[nt] = b3[n]; xbr[nt] = xproj_b[n];
    }

    const int r8 = tid >> 4;          // LN row
    const int c8 = (tid & 15) * 8;    // LN col base
    float gR[8], bR[8];
#pragma unroll
    for (int j = 0; j < 8; ++j) { gR[j] = ln_g[c8 + j]; bR[j] = ln_b[c8 + j]; }

#pragma unroll
    for (int j = 0; j < 8; ++j) {
        zS[r8][c8 + j] = zbuf[(long)(b0 + r8) * 128 + c8 + j];
        kS[r8][c8 + j] = 0.0f;
    }

    f32x4 krk[2];
    krk[0] = (f32x4){0,0,0,0}; krk[1] = (f32x4){0,0,0,0};
    const float DT = 1.0f / 32.0f;

    __syncthreads();

#pragma unroll 1
    for (int step = 0; step < 32; ++step) {
#pragma unroll 1
        for (int sub = 0; sub < 4; ++sub) {
            const int e = 2 * step + ((sub == 0) ? 0 : (sub == 3) ? 2 : 1);
            const float cin = (sub == 0) ? 0.0f : (sub == 3) ? DT : 0.5f * DT;

            // ---- LayerNorm(z + cin*k) -> hbuf[:,0:128] ----
            {
                float x[8];
                float sum = 0.f, sq = 0.f;
#pragma unroll
                for (int j = 0; j < 8; ++j) {
                    float v = zS[r8][c8 + j] + cin * kS[r8][c8 + j];
                    x[j] = v; sum += v; sq += v * v;
                }
#pragma unroll
                for (int m = 1; m < 16; m <<= 1) {
                    sum += __shfl_xor(sum, m, 16);
                    sq  += __shfl_xor(sq,  m, 16);
                }
                const float mu  = sum * (1.0f / 128.0f);
                const float var = sq * (1.0f / 128.0f) - mu * mu;
                const float inv = 1.0f / sqrtf(var + 1e-5f);
                h8f16 o;
#pragma unroll
                for (int j = 0; j < 8; ++j)
                    o[j] = (_Float16)((x[j] - mu) * inv * gR[j] + bR[j]);
                *(h8f16*)&hbuf[r8][c8] = o;
            }
            // ---- stage lerp'd past rows (K=32) ----
            if (tid < 128) {
                const float t   = (float)e * (1.0f / 64.0f);   // exact dyadic
                const float pos = t * 511.0f;                  // exact (<=15 bits)
                int i0 = (int)pos;
                if (i0 > 511) i0 = 511;
                const int i1 = (i0 < 511) ? i0 + 1 : 511;
                const float w = pos - (float)i0;
                const int rr = tid >> 3;
                const int cc = (tid & 7) * 4;
                const float* p0 = past + ((long)(b0 + rr) * 512 + i0) * 32 + cc;
                const float* p1 = past + ((long)(b0 + rr) * 512 + i1) * 32 + cc;
#pragma unroll
                for (int j = 0; j < 4; ++j)
                    bxbuf[rr][cc + j] = (_Float16)((1.0f - w) * p0[j] + w * p1[j]);
            }
            __syncthreads();

            // ---- xt = bx @ xproj_w.T + xproj_b  -> hbuf[:,128:256] ----
            {
                h8f16 a = *(const h8f16*)&bxbuf[lrow][lhi * 8];
                f32x4 a0 = {0,0,0,0}, a1 = {0,0,0,0};
                a0 = MFMA16(a, xpf[0], a0);
                a1 = MFMA16(a, xpf[1], a1);
#pragma unroll
                for (int j = 0; j < 4; ++j) {
                    hbuf[lhi * 4 + j][128 + wq * 32 + lrow]      = (_Float16)(a0[j] + xbr[0]);
                    hbuf[lhi * 4 + j][128 + wq * 32 + 16 + lrow] = (_Float16)(a1[j] + xbr[1]);
                }
            }
            __syncthreads();

            // ---- layer 1: h1 = silu(h @ w1.T + b1), K=256 ----
            {
                f32x4 a0 = {0,0,0,0}, a1 = {0,0,0,0};
#pragma unroll
                for (int ks = 0; ks < 8; ++ks) {
                    h8f16 a = *(const h8f16*)&hbuf[lrow][ks * 32 + lhi * 8];
                    a0 = MFMA16(a, w1f[0][ks], a0);
                    a1 = MFMA16(a, w1f[1][ks], a1);
                }
#pragma unroll
                for (int j = 0; j < 4; ++j) {
                    float v0 = a0[j] + b1r[0];
                    float v1 = a1[j] + b1r[1];
                    v0 = v0 / (1.0f + __expf(-v0));
                    v1 = v1 / (1.0f + __expf(-v1));
                    h1buf[lhi * 4 + j][wq * 32 + lrow]      = (_Float16)v0;
                    h1buf[lhi * 4 + j][wq * 32 + 16 + lrow] = (_Float16)v1;
                }
            }
            __syncthreads();

            // ---- layer 2: h2 = silu(h1 @ w2.T + b2), K=128 ----
            {
                f32x4 a0 = {0,0,0,0}, a1 = {0,0,0,0};
#pragma unroll
                for (int ks = 0; ks < 4; ++ks) {
                    h8f16 a = *(const h8f16*)&h1buf[lrow][ks * 32 + lhi * 8];
                    a0 = MFMA16(a, w2f[0][ks], a0);
                    a1 = MFMA16(a, w2f[1][ks], a1);
                }
#pragma unroll
                for (int j = 0; j < 4; ++j) {
                    float v0 = a0[j] + b2r[0];
                    float v1 = a1[j] + b2r[1];
                    v0 = v0 / (1.0f + __expf(-v0));
                    v1 = v1 / (1.0f + __expf(-v1));
                    h2buf[lhi * 4 + j][wq * 32 + lrow]      = (_Float16)v0;
                    h2buf[lhi * 4 + j][wq * 32 + 16 + lrow] = (_Float16)v1;
                }
            }
            __syncthreads();

            // ---- layer 3: k = h2 @ w3.T + b3, K=128; RK4 bookkeeping ----
            {
                f32x4 a0 = {0,0,0,0}, a1 = {0,0,0,0};
#pragma unroll
                for (int ks = 0; ks < 4; ++ks) {
                    h8f16 a = *(const h8f16*)&h2buf[lrow][ks * 32 + lhi * 8];
                    a0 = MFMA16(a, w3f[0][ks], a0);
                    a1 = MFMA16(a, w3f[1][ks], a1);
                }
                if (sub < 3) {
                    const float wgt = (sub == 0) ? 1.0f : 2.0f;
#pragma unroll
                    for (int j = 0; j < 4; ++j) {
                        float k0v = a0[j] + b3r[0];
                        float k1v = a1[j] + b3r[1];
                        kS[lhi * 4 + j][wq * 32 + lrow]      = k0v;
                        kS[lhi * 4 + j][wq * 32 + 16 + lrow] = k1v;
                        if (sub == 0) { krk[0][j] = k0v;        krk[1][j] = k1v; }
                        else          { krk[0][j] += wgt * k0v; krk[1][j] += wgt * k1v; }
                    }
                } else {
#pragma unroll
                    for (int j = 0; j < 4; ++j) {
                        float k0v = a0[j] + b3r[0];
                        float k1v = a1[j] + b3r[1];
                        const int rr = lhi * 4 + j;
                        zS[rr][wq * 32 + lrow]      += (DT / 6.0f) * (krk[0][j] + k0v);
                        zS[rr][wq * 32 + 16 + lrow] += (DT / 6.0f) * (krk[1][j] + k1v);
                    }
                }
            }
            __syncthreads();
        }
    }

#pragma unroll
    for (int j = 0; j < 8; ++j)
        zbuf[(long)(b0 + r8) * 128 + c8 + j] = zS[r8][c8 + j];
}

// ---------------------------------------------------------------------------
// hcat = [x_t flat (3072) | cond (128) | time-emb (128)] as f16
// grid: 2048*416/256 blocks; each thread writes one 8-element chunk
// ---------------------------------------------------------------------------
__global__ __launch_bounds__(256) void hcat_kernel(
    const float* __restrict__ x_t, const float* __restrict__ cond,
    const int* __restrict__ tvals, _Float16* __restrict__ hcat)
{
    const int gid = blockIdx.x * 256 + threadIdx.x;
    const int b  = gid / 416;
    const int j0 = (gid % 416) * 8;
    h8f16 v;
    if (j0 < 3072) {
        const float* s = x_t + (long)b * 3072 + j0;
#pragma unroll
        for (int j = 0; j < 8; ++j) v[j] = (_Float16)s[j];
    } else if (j0 < 3200) {
        const float* s = cond + (long)b * 128 + (j0 - 3072);
#pragma unroll
        for (int j = 0; j < 8; ++j) v[j] = (_Float16)s[j];
    } else {
        const float tv = (float)tvals[b];
#pragma unroll
        for (int j = 0; j < 8; ++j) {
            const int jj  = j0 - 3200 + j;
            const int idx = (jj < 64) ? jj : jj - 64;
            const float fr = expf(-9.210340371976184f * (float)idx * (1.0f / 63.0f));
            const float a  = tv * fr;
            v[j] = (_Float16)((jj < 64) ? sinf(a) : cosf(a));
        }
    }
    *(h8f16*)&hcat[(long)b * 3328 + j0] = v;
}

// ---------------------------------------------------------------------------
// Generic f16-MFMA GEMM: out(M,N) = [silu](A(M,K) @ W(N,K).T + bias)
// A is f16; W/bias fp32 (converted while staging). Tile 64x64, K-step 32.
// grid: (M/64, N/64) x 256 threads (wave q = M-quarter of the tile).
// ---------------------------------------------------------------------------
template <bool SILU, bool OUT_F16>
__global__ __launch_bounds__(256) void gemm_f16(
    const _Float16* __restrict__ A, const float* __restrict__ W,
    const float* __restrict__ bias, void* __restrict__ out,
    int M, int N, int K)
{
    __shared__ _Float16 aS[64][40];
    __shared__ _Float16 wS[64][40];
    const int mb = blockIdx.x * 64, nb = blockIdx.y * 64;
    const int tid = threadIdx.x, lane = tid & 63, wq = tid >> 6;
    const int lrow = lane & 15, lhi = lane >> 4;
    f32x4 acc[4];
#pragma unroll
    for (int nt = 0; nt < 4; ++nt) acc[nt] = (f32x4){0,0,0,0};

    const int sr = tid >> 2;          // staging row 0..63
    const int sk = (tid & 3) * 8;     // staging k 0/8/16/24

    for (int k0 = 0; k0 < K; k0 += 32) {
        {
            h8f16 v = *(const h8f16*)&A[(long)(mb + sr) * K + k0 + sk];
            *(h8f16*)&aS[sr][sk] = v;
        }
        {
            const float* s = &W[(long)(nb + sr) * K + k0 + sk];
            h8f16 v;
#pragma unroll
            for (int j = 0; j < 8; ++j) v[j] = (_Float16)s[j];
            *(h8f16*)&wS[sr][sk] = v;
        }
        __syncthreads();
        h8f16 a = *(const h8f16*)&aS[wq * 16 + lrow][lhi * 8];
#pragma unroll
        for (int nt = 0; nt < 4; ++nt) {
            h8f16 bfr = *(const h8f16*)&wS[nt * 16 + lrow][lhi * 8];
            acc[nt] = MFMA16(a, bfr, acc[nt]);
        }
        __syncthreads();
    }

#pragma unroll
    for (int nt = 0; nt < 4; ++nt) {
        const int cc = nb + nt * 16 + lrow;
        const float bv = bias[cc];
#pragma unroll
        for (int j = 0; j < 4; ++j) {
            const int rr = mb + wq * 16 + lhi * 4 + j;
            float v = acc[nt][j] + bv;
            if (SILU) v = v / (1.0f + __expf(-v));
            if (OUT_F16) ((_Float16*)out)[(long)rr * N + cc] = (_Float16)v;
            else         ((float*)out)[(long)rr * N + cc] = v;
        }
    }
}

// ---------------------------------------------------------------------------
extern "C" void kernel_launch(void* const* d_in, const int* in_sizes, int n_in,
                              void* d_out, int out_size, void* d_ws, size_t ws_size,
                              hipStream_t stream)
{
    const float* x_t     = (const float*)d_in[0];
    const float* past    = (const float*)d_in[1];
    const int*   tvals   = (const int*)d_in[2];
    const float* xproj_w = (const float*)d_in[3];
    const float* xproj_b = (const float*)d_in[4];
    const float* z0_w    = (const float*)d_in[5];
    const float* z0_b    = (const float*)d_in[6];
    const float* ln_g    = (const float*)d_in[7];
    const float* ln_b    = (const float*)d_in[8];
    const float* w1      = (const float*)d_in[9];
    const float* b1      = (const float*)d_in[10];
    const float* w2      = (const float*)d_in[11];
    const float* b2      = (const float*)d_in[12];
    const float* w3      = (const float*)d_in[13];
    const float* b3      = (const float*)d_in[14];
    const float* fw1     = (const float*)d_in[15];
    const float* fb1     = (const float*)d_in[16];
    const float* fw2     = (const float*)d_in[17];
    const float* fb2     = (const float*)d_in[18];
    const float* fw3     = (const float*)d_in[19];
    const float* fb3     = (const float*)d_in[20];

    char* ws = (char*)d_ws;
    float*     zbuf = (float*)ws;                               // 1 MB  (B*128 f32)
    _Float16*  hcat = (_Float16*)(ws + (1 << 20));              // 13.63 MB (B*3328 f16)
    _Float16*  h1   = (_Float16*)(ws + 15 * (1 << 20));         // 1 MB
    _Float16*  h2   = (_Float16*)(ws + 16 * (1 << 20));         // 1 MB

    z0_kernel<<<2048, 128, 0, stream>>>(past, xproj_w, xproj_b, z0_w, z0_b, zbuf);

    ode_kernel<<<128, 256, 0, stream>>>(past, xproj_w, xproj_b, ln_g, ln_b,
                                        w1, b1, w2, b2, w3, b3, zbuf);

    hcat_kernel<<<(2048 * 416) / 256, 256, 0, stream>>>(x_t, zbuf, tvals, hcat);

    gemm_f16<true,  true ><<<dim3(32, 4),  256, 0, stream>>>(hcat, fw1, fb1, h1, 2048, 256, 3328);
    gemm_f16<true,  true ><<<dim3(32, 4),  256, 0, stream>>>(h1,   fw2, fb2, h2, 2048, 256, 256);
    gemm_f16<false, false><<<dim3(32, 48), 256, 0, stream>>>(h2,   fw3, fb3, d_out, 2048, 3072, 256);
}

// Round 2
// 335.686 us; speedup vs baseline: 1.1867x; 1.1867x over previous
//
#include <hip/hip_runtime.h>
#include <math.h>

typedef _Float16 h8f16 __attribute__((ext_vector_type(8)));
typedef _Float16 h4f16 __attribute__((ext_vector_type(4)));
typedef float f32x4 __attribute__((ext_vector_type(4)));

#define MFMA16(a, b, c) __builtin_amdgcn_mfma_f32_16x16x32_f16((a), (b), (c), 0, 0, 0)

__device__ __forceinline__ float silu_f(float v) {
    return v * __builtin_amdgcn_rcpf(1.0f + __expf(-v));
}

// ---------------------------------------------------------------------------
// z0 = (past[:,0,:] @ xproj_w.T + xproj_b) @ z0_w.T + z0_b      (fp32 exact)
// ---------------------------------------------------------------------------
__global__ __launch_bounds__(128) void z0_kernel(
    const float* __restrict__ past,
    const float* __restrict__ xw, const float* __restrict__ xb,
    const float* __restrict__ zw, const float* __restrict__ zb,
    float* __restrict__ zbuf)
{
    __shared__ float p[32];
    __shared__ float x0[128];
    const int b = blockIdx.x;
    const int tid = threadIdx.x;
    if (tid < 32) p[tid] = past[(long)b * 512 * 32 + tid];
    __syncthreads();
    float s = xb[tid];
#pragma unroll
    for (int c = 0; c < 32; ++c) s += p[c] * xw[tid * 32 + c];
    x0[tid] = s;
    __syncthreads();
    float z = zb[tid];
    for (int k = 0; k < 128; ++k) z += x0[k] * zw[tid * 128 + k];
    zbuf[(long)b * 128 + tid] = z;
}

// ---------------------------------------------------------------------------
// ODE mega-kernel v2: 32 RK4 steps x 4 odef evals in one launch.
// grid: 128 blocks (16 batch rows) x 256 threads (4 waves; wave q owns
// output columns [32q,32q+32) of every layer).
//
// v2 structural changes vs v1 (critical-path reduction):
//  - xt GEMM folded into layer 1: xt@W1b.T == bx@Wc.T + bc with
//    Wc = W1b @ xproj_w (128x32), bc = W1b @ xproj_b. One phase + one
//    barrier removed; 26 MFMA/wave/eval.
//  - ALL 65 distinct lerped past tiles (bx) preloaded into LDS once;
//    the 128-eval serial loop performs zero global memory accesses.
// ---------------------------------------------------------------------------
__global__ __launch_bounds__(256, 1) void ode_kernel(
    const float* __restrict__ past,
    const float* __restrict__ xproj_w, const float* __restrict__ xproj_b,
    const float* __restrict__ ln_g, const float* __restrict__ ln_b,
    const float* __restrict__ w1, const float* __restrict__ b1,
    const float* __restrict__ w2, const float* __restrict__ b2,
    const float* __restrict__ w3, const float* __restrict__ b3,
    float* __restrict__ zbuf)
{
    __shared__ _Float16 bxAll[65][16][40];  // 83.2 KB: all blended past tiles
    __shared__ _Float16 hbuf[16][136];      // zn
    __shared__ _Float16 h1buf[16][136];
    __shared__ _Float16 h2buf[16][136];
    __shared__ float zS[16][132];           // ODE state
    __shared__ float kS[16][132];           // last k (for z + c*k input)

    const int tid  = threadIdx.x;
    const int lane = tid & 63;
    const int wq   = tid >> 6;
    const int lrow = lane & 15;
    const int lhi  = lane >> 4;
    const int b0   = blockIdx.x * 16;

    // ---- preload weights into register B-fragments ----
    // frag (tile nt, kstep ks): lane holds w[n][ks*32 + lhi*8 + j], n = wq*32+nt*16+lrow
    h8f16 w1f[2][4], wcf[2], w2f[2][4], w3f[2][4];
    float b1t[2], b2r[2], b3r[2];
#pragma unroll
    for (int nt = 0; nt < 2; ++nt) {
        const int n = wq * 32 + nt * 16 + lrow;
#pragma unroll
        for (int ks = 0; ks < 4; ++ks) {
            const float* s = w1 + n * 256 + ks * 32 + lhi * 8;   // W1a = w1[:, :128]
            h8f16 v;
#pragma unroll
            for (int j = 0; j < 8; ++j) v[j] = (_Float16)s[j];
            w1f[nt][ks] = v;
        }
        // Wc[n][c] = sum_k w1[n][128+k] * xproj_w[k][c];  bc = sum_k w1[n][128+k]*xb[k]
        {
            float wc[8] = {0, 0, 0, 0, 0, 0, 0, 0};
            float bc = 0.0f;
            const int c0 = lhi * 8;
            const float* w1b = w1 + n * 256 + 128;
#pragma unroll 4
            for (int k = 0; k < 128; ++k) {
                const float a = w1b[k];
                bc += a * xproj_b[k];
                const float* xr = xproj_w + k * 32 + c0;
#pragma unroll
                for (int j = 0; j < 8; ++j) wc[j] += a * xr[j];
            }
            h8f16 v;
#pragma unroll
            for (int j = 0; j < 8; ++j) v[j] = (_Float16)wc[j];
            wcf[nt] = v;
            b1t[nt] = b1[n] + bc;
        }
#pragma unroll
        for (int ks = 0; ks < 4; ++ks) {
            const float* s2 = w2 + n * 128 + ks * 32 + lhi * 8;
            const float* s3 = w3 + n * 128 + ks * 32 + lhi * 8;
            h8f16 v2, v3;
#pragma unroll
            for (int j = 0; j < 8; ++j) { v2[j] = (_Float16)s2[j]; v3[j] = (_Float16)s3[j]; }
            w2f[nt][ks] = v2; w3f[nt][ks] = v3;
        }
        b2r[nt] = b2[n]; b3r[nt] = b3[n];
    }

    const int r8 = tid >> 4;
    const int c8 = (tid & 15) * 8;
    float gR[8], bR[8];
#pragma unroll
    for (int j = 0; j < 8; ++j) { gR[j] = ln_g[c8 + j]; bR[j] = ln_b[c8 + j]; }

    // ---- preload ALL 65 blended bx tiles into LDS ----
    for (int flat = tid; flat < 65 * 128; flat += 256) {
        const int e  = flat >> 7;
        const int u  = flat & 127;
        const int r  = u >> 3;
        const int c  = (u & 7) * 4;
        const float pos = (float)e * 7.984375f;     // e*(511/64), exact
        const int i0 = (int)pos;
        const int i1 = (i0 < 511) ? i0 + 1 : 511;
        const float w = pos - (float)i0;
        const f32x4 a0 = *(const f32x4*)(past + ((long)(b0 + r) * 512 + i0) * 32 + c);
        const f32x4 a1 = *(const f32x4*)(past + ((long)(b0 + r) * 512 + i1) * 32 + c);
        h4f16 v;
#pragma unroll
        for (int j = 0; j < 4; ++j) v[j] = (_Float16)((1.0f - w) * a0[j] + w * a1[j]);
        *(h4f16*)&bxAll[e][r][c] = v;
    }

#pragma unroll
    for (int j = 0; j < 8; ++j) {
        zS[r8][c8 + j] = zbuf[(long)(b0 + r8) * 128 + c8 + j];
        kS[r8][c8 + j] = 0.0f;
    }

    f32x4 krk[2];
    krk[0] = (f32x4){0, 0, 0, 0}; krk[1] = (f32x4){0, 0, 0, 0};
    const float DT = 1.0f / 32.0f;

    __syncthreads();

#pragma unroll 1
    for (int step = 0; step < 32; ++step) {
#pragma unroll 1
        for (int sub = 0; sub < 4; ++sub) {
            const int e = 2 * step + ((sub + 1) >> 1);          // 0,1,1,2
            const float cin = (sub == 0) ? 0.0f : (sub == 3) ? DT : 0.5f * DT;

            // ---- LayerNorm(z + cin*k) -> hbuf ----
            {
                float x[8];
                float sum = 0.f, sq = 0.f;
#pragma unroll
                for (int j = 0; j < 8; ++j) {
                    float v = zS[r8][c8 + j] + cin * kS[r8][c8 + j];
                    x[j] = v; sum += v; sq += v * v;
                }
#pragma unroll
                for (int m = 1; m < 16; m <<= 1) {
                    sum += __shfl_xor(sum, m, 16);
                    sq  += __shfl_xor(sq,  m, 16);
                }
                const float mu  = sum * (1.0f / 128.0f);
                const float var = sq * (1.0f / 128.0f) - mu * mu;
                const float inv = 1.0f / sqrtf(var + 1e-5f);
                h8f16 o;
#pragma unroll
                for (int j = 0; j < 8; ++j)
                    o[j] = (_Float16)((x[j] - mu) * inv * gR[j] + bR[j]);
                *(h8f16*)&hbuf[r8][c8] = o;
            }
            __syncthreads();

            // ---- layer 1: h1 = silu(zn @ W1a.T + bx @ Wc.T + b1 + bc), 10 MFMA ----
            {
                h8f16 az[4];
#pragma unroll
                for (int ks = 0; ks < 4; ++ks)
                    az[ks] = *(const h8f16*)&hbuf[lrow][ks * 32 + lhi * 8];
                const h8f16 bx = *(const h8f16*)&bxAll[e][lrow][lhi * 8];
                f32x4 a0 = {0, 0, 0, 0}, a1 = {0, 0, 0, 0};
#pragma unroll
                for (int ks = 0; ks < 4; ++ks) {
                    a0 = MFMA16(az[ks], w1f[0][ks], a0);
                    a1 = MFMA16(az[ks], w1f[1][ks], a1);
                }
                a0 = MFMA16(bx, wcf[0], a0);
                a1 = MFMA16(bx, wcf[1], a1);
#pragma unroll
                for (int j = 0; j < 4; ++j) {
                    h1buf[lhi * 4 + j][wq * 32 + lrow]      = (_Float16)silu_f(a0[j] + b1t[0]);
                    h1buf[lhi * 4 + j][wq * 32 + 16 + lrow] = (_Float16)silu_f(a1[j] + b1t[1]);
                }
            }
            __syncthreads();

            // ---- layer 2: h2 = silu(h1 @ w2.T + b2), 8 MFMA ----
            {
                f32x4 a0 = {0, 0, 0, 0}, a1 = {0, 0, 0, 0};
#pragma unroll
                for (int ks = 0; ks < 4; ++ks) {
                    h8f16 a = *(const h8f16*)&h1buf[lrow][ks * 32 + lhi * 8];
                    a0 = MFMA16(a, w2f[0][ks], a0);
                    a1 = MFMA16(a, w2f[1][ks], a1);
                }
#pragma unroll
                for (int j = 0; j < 4; ++j) {
                    h2buf[lhi * 4 + j][wq * 32 + lrow]      = (_Float16)silu_f(a0[j] + b2r[0]);
                    h2buf[lhi * 4 + j][wq * 32 + 16 + lrow] = (_Float16)silu_f(a1[j] + b2r[1]);
                }
            }
            __syncthreads();

            // ---- layer 3: k = h2 @ w3.T + b3; RK4 bookkeeping ----
            {
                f32x4 a0 = {0, 0, 0, 0}, a1 = {0, 0, 0, 0};
#pragma unroll
                for (int ks = 0; ks < 4; ++ks) {
                    h8f16 a = *(const h8f16*)&h2buf[lrow][ks * 32 + lhi * 8];
                    a0 = MFMA16(a, w3f[0][ks], a0);
                    a1 = MFMA16(a, w3f[1][ks], a1);
                }
                if (sub < 3) {
                    const float wgt = (sub == 0) ? 1.0f : 2.0f;
#pragma unroll
                    for (int j = 0; j < 4; ++j) {
                        const float k0v = a0[j] + b3r[0];
                        const float k1v = a1[j] + b3r[1];
                        kS[lhi * 4 + j][wq * 32 + lrow]      = k0v;
                        kS[lhi * 4 + j][wq * 32 + 16 + lrow] = k1v;
                        if (sub == 0) { krk[0][j] = k0v;        krk[1][j] = k1v; }
                        else          { krk[0][j] += wgt * k0v; krk[1][j] += wgt * k1v; }
                    }
                } else {
#pragma unroll
                    for (int j = 0; j < 4; ++j) {
                        const float k0v = a0[j] + b3r[0];
                        const float k1v = a1[j] + b3r[1];
                        const int rr = lhi * 4 + j;
                        zS[rr][wq * 32 + lrow]      += (DT / 6.0f) * (krk[0][j] + k0v);
                        zS[rr][wq * 32 + 16 + lrow] += (DT / 6.0f) * (krk[1][j] + k1v);
                    }
                }
            }
            __syncthreads();
        }
    }

#pragma unroll
    for (int j = 0; j < 8; ++j)
        zbuf[(long)(b0 + r8) * 128 + c8 + j] = zS[r8][c8 + j];
}

// ---------------------------------------------------------------------------
// hcat = [x_t flat (3072) | cond (128) | time-emb (128)] as f16
// ---------------------------------------------------------------------------
__global__ __launch_bounds__(256) void hcat_kernel(
    const float* __restrict__ x_t, const float* __restrict__ cond,
    const int* __restrict__ tvals, _Float16* __restrict__ hcat)
{
    const int gid = blockIdx.x * 256 + threadIdx.x;
    const int b  = gid / 416;
    const int j0 = (gid % 416) * 8;
    h8f16 v;
    if (j0 < 3072) {
        const float* s = x_t + (long)b * 3072 + j0;
#pragma unroll
        for (int j = 0; j < 8; ++j) v[j] = (_Float16)s[j];
    } else if (j0 < 3200) {
        const float* s = cond + (long)b * 128 + (j0 - 3072);
#pragma unroll
        for (int j = 0; j < 8; ++j) v[j] = (_Float16)s[j];
    } else {
        const float tv = (float)tvals[b];
#pragma unroll
        for (int j = 0; j < 8; ++j) {
            const int jj  = j0 - 3200 + j;
            const int idx = (jj < 64) ? jj : jj - 64;
            const float fr = expf(-9.210340371976184f * (float)idx * (1.0f / 63.0f));
            const float a  = tv * fr;
            v[j] = (_Float16)((jj < 64) ? sinf(a) : cosf(a));
        }
    }
    *(h8f16*)&hcat[(long)b * 3328 + j0] = v;
}

// ---------------------------------------------------------------------------
// Generic f16-MFMA GEMM: out(M,N) = [silu](A(M,K) @ W(N,K).T + bias)
// ---------------------------------------------------------------------------
template <bool SILU, bool OUT_F16>
__global__ __launch_bounds__(256) void gemm_f16(
    const _Float16* __restrict__ A, const float* __restrict__ W,
    const float* __restrict__ bias, void* __restrict__ out,
    int M, int N, int K)
{
    __shared__ _Float16 aS[64][40];
    __shared__ _Float16 wS[64][40];
    const int mb = blockIdx.x * 64, nb = blockIdx.y * 64;
    const int tid = threadIdx.x, lane = tid & 63, wq = tid >> 6;
    const int lrow = lane & 15, lhi = lane >> 4;
    f32x4 acc[4];
#pragma unroll
    for (int nt = 0; nt < 4; ++nt) acc[nt] = (f32x4){0, 0, 0, 0};

    const int sr = tid >> 2;
    const int sk = (tid & 3) * 8;

    for (int k0 = 0; k0 < K; k0 += 32) {
        {
            h8f16 v = *(const h8f16*)&A[(long)(mb + sr) * K + k0 + sk];
            *(h8f16*)&aS[sr][sk] = v;
        }
        {
            const float* s = &W[(long)(nb + sr) * K + k0 + sk];
            h8f16 v;
#pragma unroll
            for (int j = 0; j < 8; ++j) v[j] = (_Float16)s[j];
            *(h8f16*)&wS[sr][sk] = v;
        }
        __syncthreads();
        h8f16 a = *(const h8f16*)&aS[wq * 16 + lrow][lhi * 8];
#pragma unroll
        for (int nt = 0; nt < 4; ++nt) {
            h8f16 bfr = *(const h8f16*)&wS[nt * 16 + lrow][lhi * 8];
            acc[nt] = MFMA16(a, bfr, acc[nt]);
        }
        __syncthreads();
    }

#pragma unroll
    for (int nt = 0; nt < 4; ++nt) {
        const int cc = nb + nt * 16 + lrow;
        const float bv = bias[cc];
#pragma unroll
        for (int j = 0; j < 4; ++j) {
            const int rr = mb + wq * 16 + lhi * 4 + j;
            float v = acc[nt][j] + bv;
            if (SILU) v = silu_f(v);
            if (OUT_F16) ((_Float16*)out)[(long)rr * N + cc] = (_Float16)v;
            else         ((float*)out)[(long)rr * N + cc] = v;
        }
    }
}

// ---------------------------------------------------------------------------
extern "C" void kernel_launch(void* const* d_in, const int* in_sizes, int n_in,
                              void* d_out, int out_size, void* d_ws, size_t ws_size,
                              hipStream_t stream)
{
    const float* x_t     = (const float*)d_in[0];
    const float* past    = (const float*)d_in[1];
    const int*   tvals   = (const int*)d_in[2];
    const float* xproj_w = (const float*)d_in[3];
    const float* xproj_b = (const float*)d_in[4];
    const float* z0_w    = (const float*)d_in[5];
    const float* z0_b    = (const float*)d_in[6];
    const float* ln_g    = (const float*)d_in[7];
    const float* ln_b    = (const float*)d_in[8];
    const float* w1      = (const float*)d_in[9];
    const float* b1      = (const float*)d_in[10];
    const float* w2      = (const float*)d_in[11];
    const float* b2      = (const float*)d_in[12];
    const float* w3      = (const float*)d_in[13];
    const float* b3      = (const float*)d_in[14];
    const float* fw1     = (const float*)d_in[15];
    const float* fb1     = (const float*)d_in[16];
    const float* fw2     = (const float*)d_in[17];
    const float* fb2     = (const float*)d_in[18];
    const float* fw3     = (const float*)d_in[19];
    const float* fb3     = (const float*)d_in[20];

    char* ws = (char*)d_ws;
    float*     zbuf = (float*)ws;                               // 1 MB
    _Float16*  hcat = (_Float16*)(ws + (1 << 20));              // 13.63 MB
    _Float16*  h1   = (_Float16*)(ws + 15 * (1 << 20));         // 1 MB
    _Float16*  h2   = (_Float16*)(ws + 16 * (1 << 20));         // 1 MB

    z0_kernel<<<2048, 128, 0, stream>>>(past, xproj_w, xproj_b, z0_w, z0_b, zbuf);

    ode_kernel<<<128, 256, 0, stream>>>(past, xproj_w, xproj_b, ln_g, ln_b,
                                        w1, b1, w2, b2, w3, b3, zbuf);

    hcat_kernel<<<(2048 * 416) / 256, 256, 0, stream>>>(x_t, zbuf, tvals, hcat);

    gemm_f16<true,  true ><<<dim3(32, 4),  256, 0, stream>>>(hcat, fw1, fb1, h1, 2048, 256, 3328);
    gemm_f16<true,  true ><<<dim3(32, 4),  256, 0, stream>>>(h1,   fw2, fb2, h2, 2048, 256, 256);
    gemm_f16<false, false><<<dim3(32, 48), 256, 0, stream>>>(h2,   fw3, fb3, d_out, 2048, 3072, 256);
}